// Round 8
// baseline (2093.251 us; speedup 1.0000x reference)
//
#include <hip/hip_runtime.h>
#include <stdint.h>

typedef unsigned long long u64;
typedef unsigned int u32;

#define NPTS    131072
#define NBATCH  16
#define NSAMP   1024
#define SUBS    16                 // blocks per batch
#define THREADS 256
#define PPT     32                 // points per thread
#define DET_TAG 1023u              // main loop uses tags 1..1022 on these words; 1023 unique to detection
#define CAP     48                 // sc0 polls before PERMANENT fallback to the agent line

// Packed word: [ tag:10 (bits 49..58) | key:32 (17..48) | (131071-idx):17 (0..16) ]
// key = 0 for masked-out (cand == -1), else float_bits(val)+1 (monotone for val >= 0).
// Max of packed (same tag) == reference first-max argmax (smaller index wins ties).
//
// Per-batch ws layout (1024B stride; batches never share cache lines):
//   +0    fast  slots (sc0-only ops): parity p -> u64[p*16 + sub]   (2 distinct 128B lines)
//   +512  agent slots (agent-only ops): same shape; also XCD detection + fallback.
// Each word written once per round by one lane; readers validate the embedded tag
// -> self-contained, no fences needed. Dual publish means the agent copy always
// exists; sc0 path failing in any way degrades to round-7 behavior (no deadlock).

__device__ __forceinline__ u64 ld_agent(const u64* p) {
    return __hip_atomic_load(p, __ATOMIC_RELAXED, __HIP_MEMORY_SCOPE_AGENT);
}
__device__ __forceinline__ void st_agent(u64* p, u64 v) {
    __hip_atomic_store(p, v, __ATOMIC_RELAXED, __HIP_MEMORY_SCOPE_AGENT);
}
// sc0-only global ops: bypass L1, serviced at the issuing XCD's L2 (the coherence
// point for blocks sharing that XCD). Correctness never depends on them.
__device__ __forceinline__ u64 ld_sc0(const u64* p) {
    u64 v;
    asm volatile("global_load_dwordx2 %0, %1, off sc0" : "=v"(v) : "v"(p));
    asm volatile("s_waitcnt vmcnt(0)" : "+v"(v) :: "memory");   // pin v through the wait
    return v;
}
__device__ __forceinline__ void st_sc0(u64* p, u64 v) {
    asm volatile("global_store_dwordx2 %0, %1, off sc0" :: "v"(p), "v"(v) : "memory");
}

__global__ __launch_bounds__(THREADS, 1)
void fps_kernel(const float* __restrict__ x, float* __restrict__ y, u64* __restrict__ ws)
{
    const int bid   = blockIdx.x;
    const int batch = bid & (NBATCH - 1);   // bid%8 uniform within a batch -> same XCD if round-robin
    const int sub   = bid >> 4;
    const int tid   = threadIdx.x;
    const int lane  = tid & 63;
    const int wv    = tid >> 6;

    const float* __restrict__ xb = x + (size_t)batch * (NPTS * 3);
    const int gbase = sub * 8192 + wv * 2048;

    // register-resident points + running min distance (static indexing only)
    float px_[PPT], py_[PPT], pz_[PPT], t_[PPT];
#pragma unroll
    for (int k = 0; k < PPT; ++k) {
        const int g = gbase + k * 64 + lane;
        const float a = xb[3 * g + 0];
        const float b = xb[3 * g + 1];
        const float c = xb[3 * g + 2];
        px_[k] = a; py_[k] = b; pz_[k] = c;
        // exactly as reference: ((a*a + b*b) + c*c), no FMA contraction
        const float mag = __fadd_rn(__fadd_rn(__fmul_rn(a, a), __fmul_rn(b, b)), __fmul_rn(c, c));
        t_[k] = (mag > 1e-3f) ? 1e10f : -1.0f;   // masked-out: cand == -1 forever
    }

    __shared__ u64   s_red[2][4];
    __shared__ float s_p[3];

    u64* const fastS  = ws + (size_t)batch * 128;   // 1024B per batch (u64 units)
    u64* const agentS = fastS + 64;                 // +512B

    // ---- same-XCD detection through the proven agent path (r6-exonerated code) ----
    const u32 xcc = (u32)__builtin_amdgcn_s_getreg((31 << 11) | 20) & 0xFu;  // HW_REG_XCC_ID
    if (tid == 0) st_agent(agentS + sub, ((u64)DET_TAG << 49) | xcc);
    u64 dv;
    {
        const u64* sp = agentS + (lane & 15);
        do { dv = ld_agent(sp); } while ((u32)(dv >> 49) != DET_TAG);
    }
    const bool fast = __all((int)(dv == __shfl(dv, 0)));

    float cpx = xb[0], cpy = xb[1], cpz = xb[2];   // first pick is always index 0
    if (sub == 0 && tid == 0) {
        float* yo = y + (size_t)batch * (NSAMP * 3);
        yo[0] = cpx; yo[1] = cpy; yo[2] = cpz;
    }

    bool agent_only = !fast;   // sticky, wave-uniform

    for (int it = 1; it < NSAMP; ++it) {
        // ---- update temps against current point, thread-local argmax ----
        float bv = -2.0f;
        int   bk = 0;
#pragma unroll
        for (int k = 0; k < PPT; ++k) {
            const float dx = __fsub_rn(px_[k], cpx);
            const float dy = __fsub_rn(py_[k], cpy);
            const float dz = __fsub_rn(pz_[k], cpz);
            const float d  = __fadd_rn(__fadd_rn(__fmul_rn(dx, dx), __fmul_rn(dy, dy)),
                                       __fmul_rn(dz, dz));
            const float tn = fminf(t_[k], d);
            t_[k] = tn;
            if (tn > bv) { bv = tn; bk = k; }   // strict > keeps smallest k
        }
        const int gidx = gbase + bk * 64 + lane;
        const u32 key  = (bv < 0.0f) ? 0u : (__float_as_uint(bv) + 1u);
        u64 packed = ((u64)(u32)it << 49) | ((u64)key << 17) | (u32)(131071 - gidx);

        // ---- wave reduce (max of packed, first-max tiebreak) ----
#pragma unroll
        for (int off = 32; off; off >>= 1) {
            const u64 o = __shfl_xor(packed, off);
            if (o > packed) packed = o;
        }

        const int par = it & 1;
        if (lane == 0) s_red[par][wv] = packed;   // parity-buffered: no cross-round overwrite
        __syncthreads();

        if (wv == 0) {
            if (lane == 0) {
                u64 blk = s_red[par][0];
                if (s_red[par][1] > blk) blk = s_red[par][1];
                if (s_red[par][2] > blk) blk = s_red[par][2];
                if (s_red[par][3] > blk) blk = s_red[par][3];
                if (fast) st_sc0(fastS + par * SUBS + sub, blk);  // same-XCD L2 line
                st_agent(agentS + par * SUBS + sub, blk);         // always: fallback copy
            }
            // ---- poll the 16 slots; overlap each candidate's coord fetch with
            //      waiting for stragglers (x is read-only -> cached loads safe) ----
            u64   v  = 0;
            float wx = 0.0f, wy = 0.0f, wz = 0.0f;
            bool  fresh = (lane >= SUBS);
            bool  use_agent = agent_only;
            u64*  const spF = fastS  + par * SUBS + lane;
            u64*  const spA = agentS + par * SUBS + lane;
            int   tries = 0;
            for (;;) {
                if (!fresh) {
                    v = use_agent ? ld_agent(spA) : ld_sc0(spF);
                    if ((u32)(v >> 49) == (u32)it) {
                        fresh = true;
                        const int ci = 131071 - (int)(v & 0x1FFFF);
                        wx = xb[3 * ci + 0];      // issued as soon as THIS slot is
                        wy = xb[3 * ci + 1];      // fresh; flies while others poll
                        wz = xb[3 * ci + 2];
                    }
                }
                if (__all((int)fresh)) break;
                if (!use_agent && ++tries >= CAP) use_agent = true;  // wave-uniform flip
            }
            agent_only = use_agent;               // sticky across rounds
            // ---- reduce metas over lanes 0..15 (offsets 8..1 stay in-group) ----
#pragma unroll
            for (int off = 8; off; off >>= 1) {
                const u64 o = __shfl_xor(v, off);
                if (o > v) v = o;
            }
            const u64 win  = __shfl(v, 0);
            const int widx = 131071 - (int)(win & 0x1FFFF);
            const int wsub = widx >> 13;          // owning block (8192-pt chunks)
            const float fx = __shfl(wx, wsub);    // winner's coords already fetched
            const float fy = __shfl(wy, wsub);    //   by lane wsub during the poll
            const float fz = __shfl(wz, wsub);
            if (lane == 0) {
                s_p[0] = fx; s_p[1] = fy; s_p[2] = fz;
                if (sub == 0) {
                    float* yo = y + ((size_t)batch * NSAMP + it) * 3;
                    yo[0] = fx; yo[1] = fy; yo[2] = fz;
                }
            }
        }
        __syncthreads();
        cpx = s_p[0]; cpy = s_p[1]; cpz = s_p[2];
    }
}

extern "C" void kernel_launch(void* const* d_in, const int* in_sizes, int n_in,
                              void* d_out, int out_size, void* d_ws, size_t ws_size,
                              hipStream_t stream) {
    const float* x = (const float*)d_in[0];
    float* y       = (float*)d_out;
    u64* ws        = (u64*)d_ws;   // 16 batches * 1024B = 16 KiB

    // zero all slot words every call (in-graph). Tags used are 1..1023; stale
    // content (zeros, 0xAA poison, previous replay's tags) can never spuriously
    // satisfy a round's tag check; XCD L2s are flushed/invalidated at dispatch
    // boundaries so no cross-replay sc0 staleness either.
    hipMemsetAsync(d_ws, 0, (size_t)(NBATCH * 1024), stream);

    void* args[] = { (void*)&x, (void*)&y, (void*)&ws };
    hipLaunchCooperativeKernel((void*)fps_kernel,
                               dim3(NBATCH * SUBS), dim3(THREADS),
                               args, 0, stream);
}

// Round 9
// 1919.027 us; speedup vs baseline: 1.0908x; 1.0908x over previous
//
#include <hip/hip_runtime.h>
#include <stdint.h>

typedef unsigned long long u64;
typedef unsigned int u32;

#define NPTS    131072
#define NBATCH  16
#define NSAMP   1024
#define SUBS    16                 // blocks per batch
#define THREADS 256
#define PPT     32                 // points per thread

// Packed word: [ tag:10 (bits 49..58) | key:32 (17..48) | (131071-idx):17 (0..16) ]
// key = 0 for masked-out (cand == -1), else float_bits(val)+1 (monotone for val >= 0).
// Max of packed (same tag) == reference first-max argmax (smaller index wins ties).
//
// Per-batch ws: 32 u64 at stride 1024B (parity p -> slots [p*16 .. p*16+15]).
// Each slot written once per round by one lane (relaxed agent store); pollers
// validate the embedded tag -> self-contained, no fences or ordering needed.
//
// r9 changes vs r7 (cycle-model driven):
//  * s_sleep(8) before the first poll: the first check previously raced the
//    publishers' one-way store latency and lost by ~50cy, wasting a full
//    ~1100cy round-trip. Sleeping ~512cy makes check#1 land fresh.
//  * all 4 waves poll independently and self-discover: removes the LDS
//    broadcast + second barrier (+ its exit convoy) from the critical path.
//    No LDS messaging at all -> no torn-word hazards. One barrier per round;
//    parity-buffered s_red stays safe (a wave cannot rewrite parity p before
//    every wave has passed the following round's barrier).

__device__ __forceinline__ u64 ld_agent(const u64* p) {
    return __hip_atomic_load(p, __ATOMIC_RELAXED, __HIP_MEMORY_SCOPE_AGENT);
}
__device__ __forceinline__ void st_agent(u64* p, u64 v) {
    __hip_atomic_store(p, v, __ATOMIC_RELAXED, __HIP_MEMORY_SCOPE_AGENT);
}

__global__ __launch_bounds__(THREADS, 1)
void fps_kernel(const float* __restrict__ x, float* __restrict__ y, u64* __restrict__ ws)
{
    const int bid   = blockIdx.x;
    const int batch = bid & (NBATCH - 1);
    const int sub   = bid >> 4;
    const int tid   = threadIdx.x;
    const int lane  = tid & 63;
    const int wv    = tid >> 6;

    const float* __restrict__ xb = x + (size_t)batch * (NPTS * 3);
    const int gbase = sub * 8192 + wv * 2048;

    // register-resident points + running min distance (static indexing only)
    float px_[PPT], py_[PPT], pz_[PPT], t_[PPT];
#pragma unroll
    for (int k = 0; k < PPT; ++k) {
        const int g = gbase + k * 64 + lane;
        const float a = xb[3 * g + 0];
        const float b = xb[3 * g + 1];
        const float c = xb[3 * g + 2];
        px_[k] = a; py_[k] = b; pz_[k] = c;
        // exactly as reference: ((a*a + b*b) + c*c), no FMA contraction
        const float mag = __fadd_rn(__fadd_rn(__fmul_rn(a, a), __fmul_rn(b, b)), __fmul_rn(c, c));
        t_[k] = (mag > 1e-3f) ? 1e10f : -1.0f;   // masked-out: cand == -1 forever
    }

    __shared__ u64 s_red[2][4];

    u64* const slots = ws + (size_t)batch * 128;   // 1024B per batch (u64 units)

    float cpx = xb[0], cpy = xb[1], cpz = xb[2];   // first pick is always index 0
    if (sub == 0 && tid == 0) {
        float* yo = y + (size_t)batch * (NSAMP * 3);
        yo[0] = cpx; yo[1] = cpy; yo[2] = cpz;
    }

    for (int it = 1; it < NSAMP; ++it) {
        // ---- update temps against current point, thread-local argmax ----
        float bv = -2.0f;
        int   bk = 0;
#pragma unroll
        for (int k = 0; k < PPT; ++k) {
            const float dx = __fsub_rn(px_[k], cpx);
            const float dy = __fsub_rn(py_[k], cpy);
            const float dz = __fsub_rn(pz_[k], cpz);
            const float d  = __fadd_rn(__fadd_rn(__fmul_rn(dx, dx), __fmul_rn(dy, dy)),
                                       __fmul_rn(dz, dz));
            const float tn = fminf(t_[k], d);
            t_[k] = tn;
            if (tn > bv) { bv = tn; bk = k; }   // strict > keeps smallest k
        }
        const int gidx = gbase + bk * 64 + lane;
        const u32 key  = (bv < 0.0f) ? 0u : (__float_as_uint(bv) + 1u);
        u64 packed = ((u64)(u32)it << 49) | ((u64)key << 17) | (u32)(131071 - gidx);

        // ---- wave reduce (max of packed, first-max tiebreak) ----
#pragma unroll
        for (int off = 32; off; off >>= 1) {
            const u64 o = __shfl_xor(packed, off);
            if (o > packed) packed = o;
        }

        const int par = it & 1;
        if (lane == 0) s_red[par][wv] = packed;   // parity-buffered: no cross-round overwrite
        __syncthreads();                          // the ONLY barrier per round

        if (wv == 0 && lane == 0) {
            u64 blk = s_red[par][0];
            if (s_red[par][1] > blk) blk = s_red[par][1];
            if (s_red[par][2] > blk) blk = s_red[par][2];
            if (s_red[par][3] > blk) blk = s_red[par][3];
            st_agent(slots + par * SUBS + sub, blk);
        }

        // ---- all 4 waves poll the 16 slots independently; per-lane coord
        //      fetch overlaps straggler waiting (x read-only -> cached safe) ----
        u64   v  = 0;
        float wx = 0.0f, wy = 0.0f, wz = 0.0f;
        bool  fresh = (lane >= SUBS);
        u64*  const sp = slots + par * SUBS + lane;
        __builtin_amdgcn_s_sleep(8);              // ~512cy: land check#1 after visibility
        for (;;) {
            if (!fresh) {
                v = ld_agent(sp);
                if ((u32)(v >> 49) == (u32)it) {
                    fresh = true;
                    const int ci = 131071 - (int)(v & 0x1FFFF);
                    wx = xb[3 * ci + 0];          // issued as soon as THIS slot is
                    wy = xb[3 * ci + 1];          // fresh; flies while others poll
                    wz = xb[3 * ci + 2];
                }
            }
            if (__all((int)fresh)) break;
            __builtin_amdgcn_s_sleep(2);          // back off ~128cy between re-checks
        }
        // ---- reduce metas over lanes 0..15 (offsets 8..1 stay in-group) ----
#pragma unroll
        for (int off = 8; off; off >>= 1) {
            const u64 o = __shfl_xor(v, off);
            if (o > v) v = o;
        }
        const u64 win  = __shfl(v, 0);
        const int widx = 131071 - (int)(win & 0x1FFFF);
        const int wsub = widx >> 13;              // owning block (8192-pt chunks)
        cpx = __shfl(wx, wsub);                   // winner's coords already fetched
        cpy = __shfl(wy, wsub);                   //   by lane wsub during the poll
        cpz = __shfl(wz, wsub);
        if (sub == 0 && wv == 0 && lane == 0) {
            float* yo = y + ((size_t)batch * NSAMP + it) * 3;
            yo[0] = cpx; yo[1] = cpy; yo[2] = cpz;
        }
    }
}

extern "C" void kernel_launch(void* const* d_in, const int* in_sizes, int n_in,
                              void* d_out, int out_size, void* d_ws, size_t ws_size,
                              hipStream_t stream) {
    const float* x = (const float*)d_in[0];
    float* y       = (float*)d_out;
    u64* ws        = (u64*)d_ws;   // 16 batches * 1024B = 16 KiB

    // zero all slot words every call (in-graph). Tags used are 1..1023; stale
    // content (zeros, 0xAA poison, previous replay's tags overwritten here)
    // can never spuriously satisfy a round's tag check.
    hipMemsetAsync(d_ws, 0, (size_t)(NBATCH * 1024), stream);

    void* args[] = { (void*)&x, (void*)&y, (void*)&ws };
    hipLaunchCooperativeKernel((void*)fps_kernel,
                               dim3(NBATCH * SUBS), dim3(THREADS),
                               args, 0, stream);
}